// Round 2
// baseline (11493.004 us; speedup 1.0000x reference)
//
#include <hip/hip_runtime.h>
#include <hip/hip_bf16.h>

#define B_TOT 1024
#define L_T   128
#define DIN   5
#define HD    64
#define RESN  256
#define BDN   8
#define NMAT  9
#define NROWS (NMAT * RESN)   // 2304
#define PLANE ((size_t)NROWS * RESN)  // elems per weight plane (589824)
#define BB    16              // batch per block
#define NTHR  512             // 8 waves
#define RPAD  (RESN + 8)      // bf16 row pad

typedef __attribute__((ext_vector_type(8))) short bf16x8;
typedef __attribute__((ext_vector_type(4))) float f32x4;

__device__ __forceinline__ float fast_tanh(float x) {
    float e = __expf(2.0f * x);
    return 1.0f - 2.0f * __builtin_amdgcn_rcpf(e + 1.0f);
}

// Split fp32 weights into bf16 hi + bf16 lo planes.
// Row r in [0,2304): rows 0..255 = B1, rows 256+k*256+i = B2[k][i]; contiguous in j.
__global__ void conv_w(const float* __restrict__ B1, const float* __restrict__ B2,
                       __hip_bfloat16* __restrict__ wh, __hip_bfloat16* __restrict__ wl) {
    int idx = blockIdx.x * 256 + threadIdx.x;
    float v = (idx < RESN * RESN) ? B1[idx] : B2[idx - RESN * RESN];
    __hip_bfloat16 h = __float2bfloat16(v);
    wh[idx] = h;
    wl[idx] = __float2bfloat16(v - __bfloat162float(h));
}

__global__ __launch_bounds__(NTHR, 2) void sde_main(
    const float* __restrict__ Vn,  const float* __restrict__ inc,
    const float* __restrict__ W1,  const float* __restrict__ b1,
    const float* __restrict__ W2,  const float* __restrict__ b2,
    const float* __restrict__ rho1p, const float* __restrict__ rho2p,
    const float* __restrict__ rho3p, const float* __restrict__ rho4p,
    const float* __restrict__ rho5p,
    const float* __restrict__ lam1, const float* __restrict__ lam2,
    const float* __restrict__ Wr,  const float* __restrict__ brp,
    const __hip_bfloat16* __restrict__ wbf,   // hi plane; lo plane at +PLANE
    float* __restrict__ out)
{
    __shared__ float rf32[BB][RESN];              // fp32 master r (output pass + init)
    __shared__ __hip_bfloat16 rh_lds[BB][RPAD];   // bf16 hi of r (A-frags)
    __shared__ __hip_bfloat16 rl_lds[BB][RPAD];   // bf16 lo of r (A-frags)
    __shared__ float dwsh[BB][BDN];
    __shared__ float hsh[BB][HD];

    const int tid  = threadIdx.x;
    const int w    = tid >> 6;     // wave 0..7 owns rows [32w,32w+32) of each matrix
    const int l    = tid & 63;
    const int n16  = l & 15;
    const int quad = l >> 4;
    const int b0   = blockIdx.x * BB;

    const float rho1 = rho1p[0], rho2 = rho2p[0], rho3 = rho3p[0],
                rho4 = rho4p[0], rho5 = rho5p[0];

    // ---- init: h = tanh(Vn @ W1^T + b1) ----
    for (int t = tid; t < BB * HD; t += NTHR) {
        int b = t >> 6, hh = t & 63;
        float s = b1[hh];
        #pragma unroll
        for (int d = 0; d < DIN; ++d) s += Vn[(b0 + b) * DIN + d] * W1[hh * DIN + d];
        hsh[b][hh] = fast_tanh(s);
    }
    __syncthreads();
    // ---- V = h @ W2^T + b2;  write fp32 master + bf16 hi/lo split ----
    for (int t = tid; t < BB * RESN; t += NTHR) {
        int b = t >> 8, i = t & 255;
        float s = b2[i];
        #pragma unroll 8
        for (int hh = 0; hh < HD; ++hh) s += hsh[b][hh] * W2[i * HD + hh];
        rf32[b][i] = s;
        __hip_bfloat16 hi = __float2bfloat16(s);
        rh_lds[b][i] = hi;
        rl_lds[b][i] = __float2bfloat16(s - __bfloat162float(hi));
    }
    __syncthreads();

    // per-lane persistent state. C/D layout (16x16x32): col(n)=lane&15 -> i, row(m)=quad*4+reg -> b.
    float rmast[2][4];          // fp32 master of r for i = 32w+16h+n16, b = 4*quad+reg
    float l1c[2], l2c[2][BDN];
    #pragma unroll
    for (int h = 0; h < 2; ++h) {
        int i = 32 * w + 16 * h + n16;
        l1c[h] = lam1[i];
        #pragma unroll
        for (int k = 0; k < BDN; ++k) l2c[h][k] = lam2[k * RESN + i];
        #pragma unroll
        for (int rg = 0; rg < 4; ++rg) rmast[h][rg] = rf32[quad * 4 + rg][i];
    }
    // output-pass caches: thread group of 32 handles one batch row
    const int ob = tid >> 5;   // 0..15
    const int ol = tid & 31;   // 0..31
    float wrc[8];
    #pragma unroll
    for (int j = 0; j < 8; ++j) wrc[j] = Wr[ol * 8 + j];
    const float brv = brp[0];

    for (int t = 0; t < L_T - 1; ++t) {
        // ---- phase 1: out[:, t] from fp32 r; stage dw(t) ----
        {
            float s = 0.0f;
            #pragma unroll
            for (int j = 0; j < 8; ++j) s += rf32[ob][ol * 8 + j] * wrc[j];
            #pragma unroll
            for (int off = 16; off >= 1; off >>= 1) s += __shfl_xor(s, off, 32);
            if (ol == 0) out[(b0 + ob) * L_T + t] = s + brv;
        }
        if (tid < BB * BDN) {
            int b = tid >> 3, k = tid & 7;
            float dv = inc[(b0 + b) * (L_T * BDN) + (t + 1) * BDN + k];
            if (t == 0) dv += inc[(b0 + b) * (L_T * BDN) + k];
            dwsh[b][k] = dv;
        }
        // ---- phase 2: A-frags (r hi/lo). A[m=n16][k = kk*32 + quad*8 + j] ----
        bf16x8 afh[8], afl[8];
        #pragma unroll
        for (int kk = 0; kk < 8; ++kk) {
            afh[kk] = *(const bf16x8*)&rh_lds[n16][kk * 32 + quad * 8];
            afl[kk] = *(const bf16x8*)&rl_lds[n16][kk * 32 + quad * 8];
        }
        __syncthreads();   // dwsh written->read; r LDS reads done before overwrite

        // ---- phase 3: 9 matvecs, double-bf16: (rh+rl)(Wh+Wl), 4 MFMA per k-chunk ----
        f32x4 acc[NMAT][2] = {};
        #pragma unroll
        for (int m = 0; m < NMAT; ++m) {
            #pragma unroll
            for (int h = 0; h < 2; ++h) {
                const __hip_bfloat16* wp =
                    wbf + (size_t)(m * RESN + 32 * w + 16 * h + n16) * RESN + quad * 8;
                #pragma unroll
                for (int kk = 0; kk < 8; ++kk) {
                    bf16x8 bh = *(const bf16x8*)(wp + kk * 32);
                    bf16x8 bl = *(const bf16x8*)(wp + PLANE + kk * 32);
                    acc[m][h] = __builtin_amdgcn_mfma_f32_16x16x32_bf16(afh[kk], bh, acc[m][h], 0, 0, 0);
                    acc[m][h] = __builtin_amdgcn_mfma_f32_16x16x32_bf16(afl[kk], bh, acc[m][h], 0, 0, 0);
                    acc[m][h] = __builtin_amdgcn_mfma_f32_16x16x32_bf16(afh[kk], bl, acc[m][h], 0, 0, 0);
                    acc[m][h] = __builtin_amdgcn_mfma_f32_16x16x32_bf16(afl[kk], bl, acc[m][h], 0, 0, 0);
                }
            }
        }

        // ---- phase 4: combine, advance r, rewrite fp32 + hi/lo split ----
        #pragma unroll
        for (int h = 0; h < 2; ++h) {
            int i = 32 * w + 16 * h + n16;
            #pragma unroll
            for (int rg = 0; rg < 4; ++rg) {
                int b = quad * 4 + rg;
                float drift = fast_tanh(rho1 * acc[0][h][rg] + rho2 * l1c[h]);
                float s = 0.0f;
                #pragma unroll
                for (int k = 0; k < BDN; ++k)
                    s += fast_tanh(rho3 * acc[1 + k][h][rg] + rho4 * l2c[h][k]) * dwsh[b][k];
                float rn = rmast[h][rg] + drift + rho5 * s;
                rmast[h][rg] = rn;
                rf32[b][i] = rn;
                __hip_bfloat16 hi = __float2bfloat16(rn);
                rh_lds[b][i] = hi;
                rl_lds[b][i] = __float2bfloat16(rn - __bfloat162float(hi));
            }
        }
        __syncthreads();
    }

    // ---- final output row t = 127 ----
    {
        float s = 0.0f;
        #pragma unroll
        for (int j = 0; j < 8; ++j) s += rf32[ob][ol * 8 + j] * wrc[j];
        #pragma unroll
        for (int off = 16; off >= 1; off >>= 1) s += __shfl_xor(s, off, 32);
        if (ol == 0) out[(b0 + ob) * L_T + (L_T - 1)] = s + brv;
    }
}

extern "C" void kernel_launch(void* const* d_in, const int* in_sizes, int n_in,
                              void* d_out, int out_size, void* d_ws, size_t ws_size,
                              hipStream_t stream) {
    const float* Vn   = (const float*)d_in[0];
    const float* inc  = (const float*)d_in[1];
    const float* W1   = (const float*)d_in[2];
    const float* b1   = (const float*)d_in[3];
    const float* W2   = (const float*)d_in[4];
    const float* b2   = (const float*)d_in[5];
    const float* r1   = (const float*)d_in[6];
    const float* r2   = (const float*)d_in[7];
    const float* r3   = (const float*)d_in[8];
    const float* r4   = (const float*)d_in[9];
    const float* r5   = (const float*)d_in[10];
    const float* B1   = (const float*)d_in[11];
    const float* B2   = (const float*)d_in[12];
    const float* lam1 = (const float*)d_in[13];
    const float* lam2 = (const float*)d_in[14];
    const float* Wr   = (const float*)d_in[15];
    const float* br   = (const float*)d_in[16];
    __hip_bfloat16* wh = (__hip_bfloat16*)d_ws;           // hi plane, 1.18 MB
    __hip_bfloat16* wl = wh + PLANE;                      // lo plane, 1.18 MB
    float* out = (float*)d_out;

    conv_w<<<dim3(NROWS * RESN / 256), dim3(256), 0, stream>>>(B1, B2, wh, wl);
    sde_main<<<dim3(B_TOT / BB), dim3(NTHR), 0, stream>>>(
        Vn, inc, W1, b1, W2, b2, r1, r2, r3, r4, r5, lam1, lam2, Wr, br, wh, out);
}

// Round 3
// 2528.303 us; speedup vs baseline: 4.5457x; 4.5457x over previous
//
#include <hip/hip_runtime.h>
#include <hip/hip_bf16.h>

#define B_TOT 1024
#define L_T   128
#define DIN   5
#define HD    64
#define RESN  256
#define BDN   8
#define NMAT  9
#define NROWS (NMAT * RESN)                 // 2304
#define PLANE ((size_t)NROWS * RESN)        // 589824 elems per weight plane
#define NGRP  16
#define BG    64                            // batch per group
#define FPB   16                            // features per block
#define NTHR  256                           // 4 waves, wave = 16-batch M-tile
#define WP    264                           // padded LDS row (256+8) -> <=2-way bank alias
#define GSZ   (2 * 2 * BG * RESN)           // per-group rbuf elems (2 bufs x 2 planes) = 65536
#define FLAG_BYTE_OFF ((2 * PLANE + (size_t)NGRP * GSZ) * 2)   // 4,456,448

typedef __attribute__((ext_vector_type(8))) short bf16x8;
typedef __attribute__((ext_vector_type(4))) float f32x4;

__device__ __forceinline__ float fast_tanh(float x) {
    float e = __expf(2.0f * x);
    return 1.0f - 2.0f * __builtin_amdgcn_rcpf(e + 1.0f);
}

// Split fp32 weights into bf16 hi + lo planes. Row layout: rows 0..255 = B1[i][:],
// rows 256+k*256+i = B2[k][i][:]; contiguous in j (MFMA K-dim).
__global__ void conv_w(const float* __restrict__ B1, const float* __restrict__ B2,
                       __hip_bfloat16* __restrict__ wh, __hip_bfloat16* __restrict__ wl) {
    int idx = blockIdx.x * 256 + threadIdx.x;
    float v = (idx < RESN * RESN) ? B1[idx] : B2[idx - RESN * RESN];
    __hip_bfloat16 h = __float2bfloat16(v);
    wh[idx] = h;
    wl[idx] = __float2bfloat16(v - __bfloat162float(h));
}

// Weight-stationary persistent kernel: 256 blocks (1/CU), 16 groups x 16 blocks.
// Block = 16 features x 9 matrices resident in LDS (hi+lo, 148.5 KB).
// Per step: r exchange via double-buffered global buffer + per-group release/acquire flag.
__global__ __launch_bounds__(NTHR, 1) void sde_ws(
    const float* __restrict__ Vn,  const float* __restrict__ inc,
    const float* __restrict__ W1,  const float* __restrict__ b1,
    const float* __restrict__ W2,  const float* __restrict__ b2,
    const float* __restrict__ rho1p, const float* __restrict__ rho2p,
    const float* __restrict__ rho3p, const float* __restrict__ rho4p,
    const float* __restrict__ rho5p,
    const float* __restrict__ lam1, const float* __restrict__ lam2,
    const float* __restrict__ Wr,  const float* __restrict__ brp,
    const __hip_bfloat16* __restrict__ wbf,   // hi plane; lo at +PLANE
    __hip_bfloat16* __restrict__ rball,       // exchange buffers
    unsigned int* __restrict__ flags,         // 1 counter per group (64B apart)
    float* __restrict__ out)
{
    __shared__ __hip_bfloat16 wlds[2][NMAT][FPB][WP];   // 152,064 B

    const int tid  = threadIdx.x;
    const int w    = tid >> 6;      // wave -> M-tile (batch 16w..16w+15 of group)
    const int lane = tid & 63;
    const int n16  = lane & 15;     // A: batch-in-tile / B: feature row / C: col
    const int quad = lane >> 4;
    const int bx   = blockIdx.x;
    const int g    = ((bx & 7) << 1) | (bx >> 7);   // XCD-local group heuristic
    const int fb   = (bx >> 3) & 15;                // feature-block within group
    const int f0   = fb * FPB;
    const int b0g  = g * BG;
    __hip_bfloat16* rbg = rball + (size_t)g * GSZ;
    unsigned int* flagp = flags + g * 16;

    const float rho1 = rho1p[0], rho2 = rho2p[0], rho3 = rho3p[0],
                rho4 = rho4p[0], rho5 = rho5p[0];

    // ---- phase A: h = tanh(Vn@W1^T+b1) into LDS overlay (pre-weight-load) ----
    float* hf  = (float*)&wlds[0][0][0][0];   // [64][66] = 16.9 KB
    float* vsh = hf + 64 * 66;                // [64][16] fp32 V slice
    for (int p = tid; p < BG * HD; p += NTHR) {
        int b = p >> 6, hh = p & 63;
        float s = b1[hh];
        #pragma unroll
        for (int d = 0; d < DIN; ++d) s += Vn[(b0g + b) * DIN + d] * W1[hh * DIN + d];
        hf[b * 66 + hh] = fast_tanh(s);
    }
    __syncthreads();
    // ---- phase B: V slice (16 features) for all 64 batch; publish r0 hi/lo ----
    for (int p = tid; p < BG * FPB; p += NTHR) {
        int b = p >> 4, f = p & 15;
        float s = b2[f0 + f];
        #pragma unroll 8
        for (int hh = 0; hh < HD; ++hh) s += hf[b * 66 + hh] * W2[(f0 + f) * HD + hh];
        vsh[b * 16 + f] = s;
        __hip_bfloat16 hi = __float2bfloat16(s);
        rbg[(0 * BG + b) * RESN + f0 + f] = hi;                       // buf0, hi
        rbg[(1 * BG + b) * RESN + f0 + f] =
            __float2bfloat16(s - __bfloat162float(hi));               // buf0, lo
    }
    __syncthreads();

    // ---- phase C: per-lane state + out column 0 ----
    float rmast[4];   // fp32 master r: batch = 16w+4*quad+rg, feature = f0+n16
    #pragma unroll
    for (int rg = 0; rg < 4; ++rg) rmast[rg] = vsh[(16 * w + 4 * quad + rg) * 16 + n16];
    const float l1c = lam1[f0 + n16];
    float l2c[BDN];
    #pragma unroll
    for (int k = 0; k < BDN; ++k) l2c[k] = lam2[k * RESN + f0 + n16];
    const float wr  = Wr[f0 + n16];
    const float brv = brp[0];
    #pragma unroll
    for (int rg = 0; rg < 4; ++rg) {
        float pp = wr * rmast[rg];
        #pragma unroll
        for (int off = 1; off <= 8; off <<= 1) pp += __shfl_xor(pp, off, 64);
        if (n16 == 0) {
            if (fb == 0) pp += brv;
            atomicAdd(&out[(b0g + 16 * w + 4 * quad + rg) * L_T + 0], pp);
        }
    }
    __syncthreads();
    if (tid == 0) {
        __threadfence();
        __hip_atomic_fetch_add(flagp, 1u, __ATOMIC_RELEASE, __HIP_MEMORY_SCOPE_AGENT);
    }
    // ---- phase D: load weight slice into LDS (overwrites overlay) ----
    for (int e = tid; e < 2 * NMAT * FPB * 32; e += NTHR) {   // 9216 x 16B
        int pl = (e >= 4608) ? 1 : 0;
        int e2 = e - pl * 4608;
        int nt = e2 >> 9, e3 = e2 & 511, rr = e3 >> 5, kc = e3 & 31;
        int grow = nt * RESN + f0 + rr;   // nt==0 -> B1 rows, nt>=1 -> B2[nt-1]
        uint4 v = *(const uint4*)(wbf + (size_t)pl * PLANE + (size_t)grow * RESN + kc * 8);
        *(uint4*)&wlds[pl][nt][rr][kc * 8] = v;
    }
    __syncthreads();

    // ---- main loop: r_t in buf[t&1]; write r_{t+1} to buf[(t+1)&1] ----
    for (int t = 0; t < L_T - 1; ++t) {
        if (tid == 0) {
            unsigned int want = 16u * (unsigned)(t + 1);
            unsigned int it = 0;
            while (__hip_atomic_load(flagp, __ATOMIC_ACQUIRE, __HIP_MEMORY_SCOPE_AGENT) < want) {
                __builtin_amdgcn_s_sleep(2);
                if (++it > (1u << 22)) break;   // bounded: no hang if non-resident
            }
        }
        __syncthreads();
        const int cur = t & 1, nxt = cur ^ 1;

        // A-frags (r hi/lo) straight from exchange buffer: A[m=n16][k=kk*32+quad*8+j]
        bf16x8 af[8][2];
        const __hip_bfloat16* rbc = rbg + (size_t)(cur * 2) * BG * RESN;
        #pragma unroll
        for (int kk = 0; kk < 8; ++kk) {
            af[kk][0] = *(const bf16x8*)(rbc + (0 * BG + 16 * w + n16) * RESN + kk * 32 + quad * 8);
            af[kk][1] = *(const bf16x8*)(rbc + (1 * BG + 16 * w + n16) * RESN + kk * 32 + quad * 8);
        }
        // dw for this step (per-lane, its 4 batch rows)
        float dwv[4][8];
        #pragma unroll
        for (int rg = 0; rg < 4; ++rg) {
            const size_t bglob = (size_t)(b0g + 16 * w + 4 * quad + rg) * (L_T * BDN);
            const float4 d0 = *(const float4*)(inc + bglob + (size_t)(t + 1) * BDN);
            const float4 d1 = *(const float4*)(inc + bglob + (size_t)(t + 1) * BDN + 4);
            dwv[rg][0] = d0.x; dwv[rg][1] = d0.y; dwv[rg][2] = d0.z; dwv[rg][3] = d0.w;
            dwv[rg][4] = d1.x; dwv[rg][5] = d1.y; dwv[rg][6] = d1.z; dwv[rg][7] = d1.w;
            if (t == 0) {
                const float4 e0 = *(const float4*)(inc + bglob);
                const float4 e1 = *(const float4*)(inc + bglob + 4);
                dwv[rg][0] += e0.x; dwv[rg][1] += e0.y; dwv[rg][2] += e0.z; dwv[rg][3] += e0.w;
                dwv[rg][4] += e1.x; dwv[rg][5] += e1.y; dwv[rg][6] += e1.z; dwv[rg][7] += e1.w;
            }
        }

        // 9 matvecs, double-bf16 (4 cross terms); kk-outer/nt-inner keeps acc chains apart
        f32x4 acc[NMAT] = {};
        #pragma unroll
        for (int kk = 0; kk < 8; ++kk) {
            bf16x8 bh[NMAT], bl[NMAT];
            #pragma unroll
            for (int nt = 0; nt < NMAT; ++nt) {
                bh[nt] = *(const bf16x8*)&wlds[0][nt][n16][kk * 32 + quad * 8];
                bl[nt] = *(const bf16x8*)&wlds[1][nt][n16][kk * 32 + quad * 8];
            }
            #pragma unroll
            for (int nt = 0; nt < NMAT; ++nt)
                acc[nt] = __builtin_amdgcn_mfma_f32_16x16x32_bf16(af[kk][0], bh[nt], acc[nt], 0, 0, 0);
            #pragma unroll
            for (int nt = 0; nt < NMAT; ++nt)
                acc[nt] = __builtin_amdgcn_mfma_f32_16x16x32_bf16(af[kk][1], bh[nt], acc[nt], 0, 0, 0);
            #pragma unroll
            for (int nt = 0; nt < NMAT; ++nt)
                acc[nt] = __builtin_amdgcn_mfma_f32_16x16x32_bf16(af[kk][0], bl[nt], acc[nt], 0, 0, 0);
            #pragma unroll
            for (int nt = 0; nt < NMAT; ++nt)
                acc[nt] = __builtin_amdgcn_mfma_f32_16x16x32_bf16(af[kk][1], bl[nt], acc[nt], 0, 0, 0);
        }

        // combine (wave-local: all 9 mats for this (batch,feature)), publish slice + out
        #pragma unroll
        for (int rg = 0; rg < 4; ++rg) {
            const int bl_ = 16 * w + 4 * quad + rg;
            float drift = fast_tanh(rho1 * acc[0][rg] + rho2 * l1c);
            float s = 0.0f;
            #pragma unroll
            for (int k = 0; k < BDN; ++k)
                s += fast_tanh(rho3 * acc[1 + k][rg] + rho4 * l2c[k]) * dwv[rg][k];
            float rn = rmast[rg] + drift + rho5 * s;
            rmast[rg] = rn;
            __hip_bfloat16 hi = __float2bfloat16(rn);
            rbg[((nxt * 2 + 0) * BG + bl_) * RESN + f0 + n16] = hi;
            rbg[((nxt * 2 + 1) * BG + bl_) * RESN + f0 + n16] =
                __float2bfloat16(rn - __bfloat162float(hi));
            float pp = wr * rn;
            #pragma unroll
            for (int off = 1; off <= 8; off <<= 1) pp += __shfl_xor(pp, off, 64);
            if (n16 == 0) {
                if (fb == 0) pp += brv;
                atomicAdd(&out[(b0g + bl_) * L_T + (t + 1)], pp);
            }
        }
        __syncthreads();   // all slice stores drained (vmcnt(0) before s_barrier)
        if (tid == 0) {
            __threadfence();
            __hip_atomic_fetch_add(flagp, 1u, __ATOMIC_RELEASE, __HIP_MEMORY_SCOPE_AGENT);
        }
    }
}

extern "C" void kernel_launch(void* const* d_in, const int* in_sizes, int n_in,
                              void* d_out, int out_size, void* d_ws, size_t ws_size,
                              hipStream_t stream) {
    const float* Vn   = (const float*)d_in[0];
    const float* inc  = (const float*)d_in[1];
    const float* W1   = (const float*)d_in[2];
    const float* b1   = (const float*)d_in[3];
    const float* W2   = (const float*)d_in[4];
    const float* b2   = (const float*)d_in[5];
    const float* r1   = (const float*)d_in[6];
    const float* r2   = (const float*)d_in[7];
    const float* r3   = (const float*)d_in[8];
    const float* r4   = (const float*)d_in[9];
    const float* r5   = (const float*)d_in[10];
    const float* B1   = (const float*)d_in[11];
    const float* B2   = (const float*)d_in[12];
    const float* lam1 = (const float*)d_in[13];
    const float* lam2 = (const float*)d_in[14];
    const float* Wr   = (const float*)d_in[15];
    const float* br   = (const float*)d_in[16];

    __hip_bfloat16* wh    = (__hip_bfloat16*)d_ws;        // 2 planes, 2.36 MB
    __hip_bfloat16* rball = wh + 2 * PLANE;               // 16 groups x 128 KB
    unsigned int*   flags = (unsigned int*)((char*)d_ws + FLAG_BYTE_OFF);
    float* out = (float*)d_out;

    hipMemsetAsync(out, 0, (size_t)B_TOT * L_T * sizeof(float), stream);
    hipMemsetAsync(flags, 0, NGRP * 16 * sizeof(unsigned int), stream);
    conv_w<<<dim3(NROWS * RESN / 256), dim3(256), 0, stream>>>(B1, B2, wh, wh + PLANE);
    sde_ws<<<dim3(256), dim3(NTHR), 0, stream>>>(
        Vn, inc, W1, b1, W2, b2, r1, r2, r3, r4, r5, lam1, lam2, Wr, br,
        wh, rball, flags, out);
}

// Round 4
// 1716.861 us; speedup vs baseline: 6.6942x; 1.4726x over previous
//
#include <hip/hip_runtime.h>
#include <hip/hip_bf16.h>

#define B_TOT 1024
#define L_T   128
#define DIN   5
#define HD    64
#define RESN  256
#define BDN   8
#define NMAT  9
#define NROWS (NMAT * RESN)                 // 2304
#define PLANE ((size_t)NROWS * RESN)        // 589824 elems per weight plane
#define NGRP  16
#define BG    64                            // batch per group
#define FPB   16                            // features per block
#define NTHR  256                           // 4 waves, wave = 16-batch M-tile
#define RB_GRP (2 * BG * RESN)              // uints per group (2 bufs, hi|lo packed)
#define WS_RB_OFF  (2 * PLANE * 2)          // bytes: after weight planes (2,359,296)
#define WS_FLAG_OFF (WS_RB_OFF + (size_t)NGRP * RB_GRP * 4)   // + 2,097,152

typedef __attribute__((ext_vector_type(8))) short bf16x8;
typedef __attribute__((ext_vector_type(4))) float f32x4;
typedef __attribute__((ext_vector_type(4))) unsigned int u32x4;

__device__ __forceinline__ float fast_tanh(float x) {
    float e = __expf(2.0f * x);
    return 1.0f - 2.0f * __builtin_amdgcn_rcpf(e + 1.0f);
}

__device__ __forceinline__ unsigned pack_hilo(float v, float* hif_out) {
    __hip_bfloat16 hi = __float2bfloat16(v);
    float hif = __bfloat162float(hi);
    __hip_bfloat16 lo = __float2bfloat16(v - hif);
    if (hif_out) *hif_out = hif;
    return (unsigned)__builtin_bit_cast(unsigned short, hi) |
           ((unsigned)__builtin_bit_cast(unsigned short, lo) << 16);
}

// Split fp32 weights into bf16 hi + lo planes (row-major, contiguous in j).
__global__ void conv_w(const float* __restrict__ B1, const float* __restrict__ B2,
                       __hip_bfloat16* __restrict__ wh, __hip_bfloat16* __restrict__ wl) {
    int idx = blockIdx.x * 256 + threadIdx.x;
    float v = (idx < RESN * RESN) ? B1[idx] : B2[idx - RESN * RESN];
    __hip_bfloat16 h = __float2bfloat16(v);
    wh[idx] = h;
    wl[idx] = __float2bfloat16(v - __bfloat162float(h));
}

// Weight-stationary persistent kernel. 256 blocks (1/CU), 16 groups x 16 blocks.
// Sync: per-group monotone counter, ALL relaxed agent-scope atomics (no acquire/
// release -> no buffer_inv/buffer_wbl2). r exchanged as agent-relaxed atomic
// dword stores/loads (hi|lo bf16 packed) -> per-access MALL coherence.
__global__ __launch_bounds__(NTHR, 1) void sde_ws(
    const float* __restrict__ Vn,  const float* __restrict__ inc,
    const float* __restrict__ W1,  const float* __restrict__ b1,
    const float* __restrict__ W2,  const float* __restrict__ b2,
    const float* __restrict__ rho1p, const float* __restrict__ rho2p,
    const float* __restrict__ rho3p, const float* __restrict__ rho4p,
    const float* __restrict__ rho5p,
    const float* __restrict__ lam1, const float* __restrict__ lam2,
    const float* __restrict__ Wr,  const float* __restrict__ brp,
    const __hip_bfloat16* __restrict__ wbf,   // hi plane; lo at +PLANE
    unsigned int* __restrict__ rbu,           // exchange: [grp][buf][b][feat] packed
    unsigned int* __restrict__ flags,
    float* __restrict__ out)
{
    // fragment-major weight slice: read addr = base + lane*16B -> conflict-free b128
    __shared__ __align__(16) short wlds[2][NMAT][8][64][8];   // 147,456 B

    const int tid  = threadIdx.x;
    const int w    = tid >> 6;
    const int lane = tid & 63;
    const int n16  = lane & 15;
    const int quad = lane >> 4;
    const int bx   = blockIdx.x;
    const int g    = ((bx & 7) << 1) | (bx >> 7);   // 16 blocks/group, same XCD (heuristic, perf-only)
    const int fb   = (bx >> 3) & 15;
    const int f0   = fb * FPB;
    const int b0g  = g * BG;
    unsigned int* rbg   = rbu + (size_t)g * RB_GRP;
    unsigned int* flagp = flags + g * 16;

    const float rho1 = rho1p[0], rho2 = rho2p[0], rho3 = rho3p[0],
                rho4 = rho4p[0], rho5 = rho5p[0];

    // ---- phase A: h = tanh(Vn@W1^T+b1) into LDS overlay ----
    float* hf  = (float*)&wlds[0][0][0][0][0];   // [64][66]
    float* vsh = hf + 64 * 66;                   // [64][16]
    for (int p = tid; p < BG * HD; p += NTHR) {
        int b = p >> 6, hh = p & 63;
        float s = b1[hh];
        #pragma unroll
        for (int d = 0; d < DIN; ++d) s += Vn[(b0g + b) * DIN + d] * W1[hh * DIN + d];
        hf[b * 66 + hh] = fast_tanh(s);
    }
    __syncthreads();
    // ---- phase B: V slice; publish r0 (packed, agent-relaxed stores) ----
    for (int p = tid; p < BG * FPB; p += NTHR) {
        int b = p >> 4, f = p & 15;
        float s = b2[f0 + f];
        #pragma unroll 8
        for (int hh = 0; hh < HD; ++hh) s += hf[b * 66 + hh] * W2[(f0 + f) * HD + hh];
        vsh[b * 16 + f] = s;
        unsigned pv = pack_hilo(s, nullptr);
        __hip_atomic_store(&rbg[(0 * BG + b) * RESN + f0 + f], pv,
                           __ATOMIC_RELAXED, __HIP_MEMORY_SCOPE_AGENT);
    }
    __syncthreads();

    // ---- phase C: per-lane state + out column 0 ----
    float rmast[4];
    #pragma unroll
    for (int rg = 0; rg < 4; ++rg) rmast[rg] = vsh[(16 * w + 4 * quad + rg) * 16 + n16];
    const float l1c = lam1[f0 + n16];
    float l2c[BDN];
    #pragma unroll
    for (int k = 0; k < BDN; ++k) l2c[k] = lam2[k * RESN + f0 + n16];
    const float wr  = Wr[f0 + n16];
    const float brv = brp[0];
    #pragma unroll
    for (int rg = 0; rg < 4; ++rg) {
        float pp = wr * rmast[rg];
        #pragma unroll
        for (int off = 1; off <= 8; off <<= 1) pp += __shfl_xor(pp, off, 64);
        if (n16 == 0) {
            if (fb == 0) pp += brv;
            atomicAdd(&out[(b0g + 16 * w + 4 * quad + rg) * L_T + 0], pp);
        }
    }
    __syncthreads();
    asm volatile("s_waitcnt vmcnt(0)" ::: "memory");   // r0 stores acked at coherence point
    if (tid == 0)
        __hip_atomic_fetch_add(flagp, 1u, __ATOMIC_RELAXED, __HIP_MEMORY_SCOPE_AGENT);

    // ---- phase D: weight slice -> fragment-major LDS ----
    for (int e = tid; e < 2 * NMAT * 8 * 64; e += NTHR) {   // 9216 x 16B
        int l  = e & 63;
        int kk = (e >> 6) & 7;
        int m  = e >> 9;                  // 0..17
        int pl = (m >= NMAT) ? 1 : 0;
        int nt = m - pl * NMAT;
        const uint4* src = (const uint4*)(wbf + (size_t)pl * PLANE +
            (size_t)(nt * RESN + f0 + (l & 15)) * RESN + kk * 32 + (l >> 4) * 8);
        *(uint4*)&wlds[pl][nt][kk][l][0] = *src;
    }
    __syncthreads();

    // ---- main loop ----
    for (int t = 0; t < L_T - 1; ++t) {
        if (tid == 0) {
            unsigned want = 16u * (unsigned)(t + 1);
            unsigned it = 0;
            while (__hip_atomic_load(flagp, __ATOMIC_RELAXED, __HIP_MEMORY_SCOPE_AGENT) < want) {
                __builtin_amdgcn_s_sleep(2);
                if (++it > (1u << 22)) break;   // bounded: no hang if non-resident
            }
        }
        __syncthreads();
        const int cur = t & 1, nxt = cur ^ 1;

        // A-frags: agent-relaxed dword loads of packed r, unpack via v_perm.
        // A[m=n16][k=kk*32+quad*8+j] ; element = r[16w+n16][kk*32+quad*8+j]
        bf16x8 afh[8], afl[8];
        {
            const unsigned int* rbc = rbg + (size_t)(cur * BG + 16 * w + n16) * RESN + quad * 8;
            #pragma unroll
            for (int kk = 0; kk < 8; ++kk) {
                unsigned u[8];
                #pragma unroll
                for (int j = 0; j < 8; ++j)
                    u[j] = __hip_atomic_load(&rbc[kk * 32 + j],
                                             __ATOMIC_RELAXED, __HIP_MEMORY_SCOPE_AGENT);
                u32x4 hw, lw;
                #pragma unroll
                for (int j = 0; j < 4; ++j) {
                    hw[j] = __builtin_amdgcn_perm(u[2 * j + 1], u[2 * j], 0x05040100u); // low16s
                    lw[j] = __builtin_amdgcn_perm(u[2 * j + 1], u[2 * j], 0x07060302u); // high16s
                }
                afh[kk] = __builtin_bit_cast(bf16x8, hw);
                afl[kk] = __builtin_bit_cast(bf16x8, lw);
            }
        }
        // dw for this step
        float dwv[4][8];
        #pragma unroll
        for (int rg = 0; rg < 4; ++rg) {
            const size_t bglob = (size_t)(b0g + 16 * w + 4 * quad + rg) * (L_T * BDN);
            const float4 d0 = *(const float4*)(inc + bglob + (size_t)(t + 1) * BDN);
            const float4 d1 = *(const float4*)(inc + bglob + (size_t)(t + 1) * BDN + 4);
            dwv[rg][0] = d0.x; dwv[rg][1] = d0.y; dwv[rg][2] = d0.z; dwv[rg][3] = d0.w;
            dwv[rg][4] = d1.x; dwv[rg][5] = d1.y; dwv[rg][6] = d1.z; dwv[rg][7] = d1.w;
            if (t == 0) {
                const float4 e0 = *(const float4*)(inc + bglob);
                const float4 e1 = *(const float4*)(inc + bglob + 4);
                dwv[rg][0] += e0.x; dwv[rg][1] += e0.y; dwv[rg][2] += e0.z; dwv[rg][3] += e0.w;
                dwv[rg][4] += e1.x; dwv[rg][5] += e1.y; dwv[rg][6] += e1.z; dwv[rg][7] += e1.w;
            }
        }

        // 9 matvecs, 3-term double-bf16: ah*bh + al*bh + ah*bl  (al*bl ~2^-16, dropped)
        f32x4 acc[NMAT] = {};
        #pragma unroll
        for (int kk = 0; kk < 8; ++kk) {
            bf16x8 bh[NMAT], bl[NMAT];
            #pragma unroll
            for (int nt = 0; nt < NMAT; ++nt) {
                bh[nt] = *(const bf16x8*)&wlds[0][nt][kk][lane][0];
                bl[nt] = *(const bf16x8*)&wlds[1][nt][kk][lane][0];
            }
            #pragma unroll
            for (int nt = 0; nt < NMAT; ++nt)
                acc[nt] = __builtin_amdgcn_mfma_f32_16x16x32_bf16(afh[kk], bh[nt], acc[nt], 0, 0, 0);
            #pragma unroll
            for (int nt = 0; nt < NMAT; ++nt)
                acc[nt] = __builtin_amdgcn_mfma_f32_16x16x32_bf16(afl[kk], bh[nt], acc[nt], 0, 0, 0);
            #pragma unroll
            for (int nt = 0; nt < NMAT; ++nt)
                acc[nt] = __builtin_amdgcn_mfma_f32_16x16x32_bf16(afh[kk], bl[nt], acc[nt], 0, 0, 0);
        }

        // combine, publish slice (agent-relaxed packed stores) + out column t+1
        #pragma unroll
        for (int rg = 0; rg < 4; ++rg) {
            const int bl_ = 16 * w + 4 * quad + rg;
            float drift = fast_tanh(rho1 * acc[0][rg] + rho2 * l1c);
            float s = 0.0f;
            #pragma unroll
            for (int k = 0; k < BDN; ++k)
                s += fast_tanh(rho3 * acc[1 + k][rg] + rho4 * l2c[k]) * dwv[rg][k];
            float rn = rmast[rg] + drift + rho5 * s;
            rmast[rg] = rn;
            unsigned pv = pack_hilo(rn, nullptr);
            __hip_atomic_store(&rbg[(nxt * BG + bl_) * RESN + f0 + n16], pv,
                               __ATOMIC_RELAXED, __HIP_MEMORY_SCOPE_AGENT);
            float pp = wr * rn;
            #pragma unroll
            for (int off = 1; off <= 8; off <<= 1) pp += __shfl_xor(pp, off, 64);
            if (n16 == 0) {
                if (fb == 0) pp += brv;
                atomicAdd(&out[(b0g + bl_) * L_T + (t + 1)], pp);
            }
        }
        asm volatile("s_waitcnt vmcnt(0)" ::: "memory");   // every thread: stores acked
        __syncthreads();
        if (tid == 0)
            __hip_atomic_fetch_add(flagp, 1u, __ATOMIC_RELAXED, __HIP_MEMORY_SCOPE_AGENT);
    }
}

extern "C" void kernel_launch(void* const* d_in, const int* in_sizes, int n_in,
                              void* d_out, int out_size, void* d_ws, size_t ws_size,
                              hipStream_t stream) {
    const float* Vn   = (const float*)d_in[0];
    const float* inc  = (const float*)d_in[1];
    const float* W1   = (const float*)d_in[2];
    const float* b1   = (const float*)d_in[3];
    const float* W2   = (const float*)d_in[4];
    const float* b2   = (const float*)d_in[5];
    const float* r1   = (const float*)d_in[6];
    const float* r2   = (const float*)d_in[7];
    const float* r3   = (const float*)d_in[8];
    const float* r4   = (const float*)d_in[9];
    const float* r5   = (const float*)d_in[10];
    const float* B1   = (const float*)d_in[11];
    const float* B2   = (const float*)d_in[12];
    const float* lam1 = (const float*)d_in[13];
    const float* lam2 = (const float*)d_in[14];
    const float* Wr   = (const float*)d_in[15];
    const float* br   = (const float*)d_in[16];

    __hip_bfloat16* wh    = (__hip_bfloat16*)d_ws;
    unsigned int*   rbu   = (unsigned int*)((char*)d_ws + WS_RB_OFF);
    unsigned int*   flags = (unsigned int*)((char*)d_ws + WS_FLAG_OFF);
    float* out = (float*)d_out;

    hipMemsetAsync(out, 0, (size_t)B_TOT * L_T * sizeof(float), stream);
    hipMemsetAsync(flags, 0, NGRP * 16 * sizeof(unsigned int), stream);
    conv_w<<<dim3(NROWS * RESN / 256), dim3(256), 0, stream>>>(B1, B2, wh, wh + PLANE);
    sde_ws<<<dim3(256), dim3(NTHR), 0, stream>>>(
        Vn, inc, W1, b1, W2, b2, r1, r2, r3, r4, r5, lam1, lam2, Wr, br,
        wh, rbu, flags, out);
}